// Round 4
// baseline (56.468 us; speedup 1.0000x reference)
//
#include <hip/hip_runtime.h>
#include <stdint.h>

#define B 64
#define N 32
#define K 16
#define NUM_WORDS 65536
#define BLOCKS 512
#define WPB 128            // words per block
#define LLR_PAD 65         // padded stride for transpose staging

typedef unsigned long long u64;

static __device__ __forceinline__ u64 umax64(u64 a, u64 b) { return a > b ? a : b; }

// Fused kernel: lane l = batch l within each wave; wave processes words
// together (cw wave-uniform -> SALU nibble extraction). Per-(block,batch)
// best key -> ws_keys[block][batch] (coalesced). Last block (atomic counter)
// reduces all keys and writes the decoded words.
__global__ __launch_bounds__(256) void mdd_fused(
    const float* __restrict__ noisy,   // [B][N]
    const int* __restrict__ G,         // [K][N]
    const float* __restrict__ sigma2,  // [1]
    u64* __restrict__ ws_keys,         // [BLOCKS][B]
    uint32_t* __restrict__ counter,    // zeroed via hipMemsetAsync each launch
    float* __restrict__ out)           // [B][K]
{
    __shared__ uint32_t g_rows[K];
    __shared__ __align__(16) uint32_t cw_lds[WPB];
    __shared__ float T_lds[8 * 16 * 64];       // [j][v][lane] 32 KB
    __shared__ float llr_t[N * LLR_PAD];       // [n][b] padded
    __shared__ float bestf_lds[4 * 64];
    __shared__ uint32_t bestw_lds[4 * 64];
    __shared__ u64 part_lds[4 * 64];           // reducer partials [q][b]
    __shared__ uint32_t w_lds[B];
    __shared__ uint32_t flag_lds;

    const int tid = threadIdx.x;
    const int l = tid & 63;
    const int wv = tid >> 6;

    // Pack G rows into 32-bit masks (bit n = G[k][n] & 1)
    if (tid < K) {
        uint32_t r = 0;
        #pragma unroll
        for (int n = 0; n < N; ++n)
            r |= (uint32_t)(G[tid * N + n] & 1) << n;
        g_rows[tid] = r;
    }

    // Coalesced load of noisy, transposed into padded LDS: llr_t[n][b]
    const float scale = -4.0f / sigma2[0];
    for (int i = tid; i < B * N; i += 256) {
        int n = i & 31, bb = i >> 5;
        llr_t[n * LLR_PAD + bb] = scale * noisy[i];
    }
    __syncthreads();

    // Codewords for this block's 128 words
    if (tid < WPB) {
        uint32_t w = blockIdx.x * WPB + tid;
        uint32_t cw = 0;
        #pragma unroll
        for (int k = 0; k < K; ++k)
            cw ^= g_rows[k] & (0u - ((w >> k) & 1u));
        cw_lds[tid] = cw;
    }

    // Nibble tables: T[j][v][l] = sum_i s(v_i)*llr[4j+i], s(b)=1-2b, built as
    // balanced exactly-negated adds (bit-identical for identical codewords).
    for (int j = wv; j < 8; j += 4) {
        float l0 = llr_t[(4 * j + 0) * LLR_PAD + l];
        float l1 = llr_t[(4 * j + 1) * LLR_PAD + l];
        float l2 = llr_t[(4 * j + 2) * LLR_PAD + l];
        float l3 = llr_t[(4 * j + 3) * LLR_PAD + l];
        float A[4] = { l0 + l1, -l0 + l1, l0 - l1, -l0 - l1 };
        float C[4] = { l2 + l3, -l2 + l3, l2 - l3, -l2 - l3 };
        float* Tj = &T_lds[j * 1024 + l];
        #pragma unroll
        for (int v = 0; v < 16; ++v)
            Tj[v * 64] = A[v & 3] + C[v >> 2];
    }
    __syncthreads();

    // Main loop: 32 words/thread, strict > with ascending w => first-wins.
    // cw is wave-uniform: readfirstlane forces nibble math onto the SALU.
    const uint4* cw4 = reinterpret_cast<const uint4*>(cw_lds);
    const float* Tl = &T_lds[l];
    float bestf = -INFINITY;
    uint32_t bestw = 0;
    const uint32_t wbase = blockIdx.x * WPB + wv * 32;

    #pragma unroll
    for (int wq = 0; wq < 8; ++wq) {
        uint4 c4 = cw4[wv * 8 + wq];
        #pragma unroll
        for (int e = 0; e < 4; ++e) {
            uint32_t cwv = (e == 0) ? c4.x : (e == 1) ? c4.y : (e == 2) ? c4.z : c4.w;
            uint32_t cw = __builtin_amdgcn_readfirstlane(cwv);
            float r0 = Tl[0 * 1024 + ((cw >> 0) & 15u) * 64];
            float r1 = Tl[1 * 1024 + ((cw >> 4) & 15u) * 64];
            float r2 = Tl[2 * 1024 + ((cw >> 8) & 15u) * 64];
            float r3 = Tl[3 * 1024 + ((cw >> 12) & 15u) * 64];
            float r4 = Tl[4 * 1024 + ((cw >> 16) & 15u) * 64];
            float r5 = Tl[5 * 1024 + ((cw >> 20) & 15u) * 64];
            float r6 = Tl[6 * 1024 + ((cw >> 24) & 15u) * 64];
            float r7 = Tl[7 * 1024 + ((cw >> 28) & 15u) * 64];
            float c = ((r0 + r1) + (r2 + r3)) + ((r4 + r5) + (r6 + r7));
            uint32_t w = wbase + wq * 4 + e;
            bool g = c > bestf;
            bestw = g ? w : bestw;
            bestf = g ? c : bestf;
        }
    }

    bestf_lds[wv * 64 + l] = bestf;
    bestw_lds[wv * 64 + l] = bestw;
    __syncthreads();

    // Merge 4 waves (ascending w ranges; strict > keeps lower w), store key
    if (tid < B) {
        float f = bestf_lds[tid];
        uint32_t w = bestw_lds[tid];
        #pragma unroll
        for (int v = 1; v < 4; ++v) {
            float f2 = bestf_lds[v * 64 + tid];
            uint32_t w2 = bestw_lds[v * 64 + tid];
            bool g = f2 > f;
            w = g ? w2 : w;
            f = g ? f2 : f;
        }
        uint32_t bits = __float_as_uint(f);
        uint32_t mono = (bits & 0x80000000u) ? ~bits : (bits | 0x80000000u);
        u64 key = ((u64)mono << 16) | (u64)(0xFFFFu - w);
        ws_keys[blockIdx.x * B + tid] = key;   // coalesced 512B store
    }

    // Signal completion (release), elect the last block
    __threadfence();
    __syncthreads();
    if (tid == 0) {
        uint32_t old = atomicAdd(counter, 1u);
        flag_lds = (old == BLOCKS - 1) ? 1u : 0u;
    }
    __syncthreads();
    if (!flag_lds) return;

    // Last block: acquire, reduce 512 keys per batch, decode, write out
    __threadfence();
    {
        const int q = tid >> 6, b = tid & 63;
        const u64* p = ws_keys + (size_t)q * 128 * B + b;
        u64 m = 0;
        #pragma unroll 8
        for (int i = 0; i < 128; ++i)          // coalesced: lanes = batches
            m = umax64(m, p[(size_t)i * B]);
        part_lds[q * 64 + b] = m;
    }
    __syncthreads();
    if (tid < B) {
        u64 f = umax64(umax64(part_lds[tid], part_lds[64 + tid]),
                       umax64(part_lds[128 + tid], part_lds[192 + tid]));
        w_lds[tid] = 0xFFFFu - (uint32_t)(f & 0xFFFFu);
    }
    __syncthreads();
    for (int i = tid; i < B * K; i += 256) {   // coalesced 4 floats/thread
        int b2 = i >> 4, kk = i & 15;
        out[i] = (float)((w_lds[b2] >> kk) & 1u);
    }
}

extern "C" void kernel_launch(void* const* d_in, const int* in_sizes, int n_in,
                              void* d_out, int out_size, void* d_ws, size_t ws_size,
                              hipStream_t stream) {
    const float* noisy = (const float*)d_in[0];
    const int* G = (const int*)d_in[1];
    const float* sigma2 = (const float*)d_in[2];
    float* out = (float*)d_out;
    u64* ws_keys = (u64*)d_ws;
    uint32_t* counter = (uint32_t*)((char*)d_ws + (size_t)BLOCKS * B * 8);

    (void)in_sizes; (void)n_in; (void)out_size; (void)ws_size;

    hipMemsetAsync(counter, 0, 4, stream);
    mdd_fused<<<BLOCKS, 256, 0, stream>>>(noisy, G, sigma2, ws_keys, counter, out);
}

// Round 6
// 26.759 us; speedup vs baseline: 2.1103x; 2.1103x over previous
//
#include <hip/hip_runtime.h>
#include <stdint.h>

#define B 64
#define N 32
#define K 16
#define NUM_WORDS 65536
#define BLOCKS 512
#define WPB 128            // words per block
#define LLR_PAD 65         // padded stride for transpose staging
#define NTAB 5             // nibbles 0..4 (bits 0..19) via LDS tables
#define NV 12              // bits 20..31 via VALU sign-xor
#define SLOT_STRIDE 8      // u64s -> 64B between slots (independent lines)

typedef unsigned long long u64;

// Kernel 1: lane l = batch l; wave processes its 32 words together.
// corr = 5 LDS nibble lookups + 12 in-register sign-xor adds (parallel pipes).
// Per-(block,batch) best -> device-scope atomicMax into padded slots.
// Cross-kernel visibility via the launch boundary (no fences).
__global__ __launch_bounds__(256) void mdd_corr(
    const float* __restrict__ noisy,   // [B][N]
    const int* __restrict__ G,         // [K][N]
    const float* __restrict__ sigma2,  // [1]
    u64* __restrict__ slots)           // [B*SLOT_STRIDE], zeroed per launch
{
    __shared__ uint32_t g_rows[K];
    __shared__ __align__(16) uint32_t cw_lds[WPB];
    __shared__ float T_lds[NTAB * 16 * 64];    // 20 KB [j][v][lane]
    __shared__ float llr_t[N * LLR_PAD];       // [n][b] padded
    __shared__ float bestf_lds[4 * 64];
    __shared__ uint32_t bestw_lds[4 * 64];

    const int tid = threadIdx.x;
    const int l = tid & 63;
    const int wv = tid >> 6;

    // Pack G rows into 32-bit masks (bit n = G[k][n] & 1)
    if (tid < K) {
        const int4* G4 = reinterpret_cast<const int4*>(G) + tid * 8;
        uint32_t r = 0;
        #pragma unroll
        for (int m = 0; m < 8; ++m) {
            int4 gv = G4[m];
            r |= (uint32_t)(gv.x & 1) << (4 * m + 0);
            r |= (uint32_t)(gv.y & 1) << (4 * m + 1);
            r |= (uint32_t)(gv.z & 1) << (4 * m + 2);
            r |= (uint32_t)(gv.w & 1) << (4 * m + 3);
        }
        g_rows[tid] = r;
    }

    // Coalesced load of noisy, transposed into padded LDS: llr_t[n][b]
    const float scale = -4.0f / sigma2[0];
    for (int i = tid; i < B * N; i += 256) {
        int n = i & 31, bb = i >> 5;
        llr_t[n * LLR_PAD + bb] = scale * noisy[i];
    }
    __syncthreads();

    // Codewords for this block's 128 words
    if (tid < WPB) {
        uint32_t w = blockIdx.x * WPB + tid;
        uint32_t cw = 0;
        #pragma unroll
        for (int k = 0; k < K; ++k)
            cw ^= g_rows[k] & (0u - ((w >> k) & 1u));
        cw_lds[tid] = cw;
    }

    // Nibble tables for bits 0..19: T[j][v][l] = sum_i s(v_i)*llr[l][4j+i],
    // s(b)=1-2b, balanced exactly-negated adds (bit-identical for equal cw).
    for (int j = wv; j < NTAB; j += 4) {
        float l0 = llr_t[(4 * j + 0) * LLR_PAD + l];
        float l1 = llr_t[(4 * j + 1) * LLR_PAD + l];
        float l2 = llr_t[(4 * j + 2) * LLR_PAD + l];
        float l3 = llr_t[(4 * j + 3) * LLR_PAD + l];
        float A[4] = { l0 + l1, -l0 + l1, l0 - l1, -l0 - l1 };
        float C[4] = { l2 + l3, -l2 + l3, l2 - l3, -l2 - l3 };
        float* Tj = &T_lds[j * 1024 + l];
        #pragma unroll
        for (int v = 0; v < 16; ++v)
            Tj[v * 64] = A[v & 3] + C[v >> 2];
    }

    // This lane's batch LLR bit-patterns for bits 20..31 (VALU path)
    uint32_t lau[NV];
    #pragma unroll
    for (int v = 0; v < NV; ++v)
        lau[v] = __float_as_uint(llr_t[(4 * NTAB + v) * LLR_PAD + l]);
    __syncthreads();

    // Main loop: 32 words/thread, strict > with ascending w => first-wins
    const uint4* cw4 = reinterpret_cast<const uint4*>(cw_lds);
    const float* Tl = &T_lds[l];
    float bestf = -INFINITY;
    uint32_t bestw = 0;
    const uint32_t wbase = blockIdx.x * WPB + wv * 32;

    #pragma unroll
    for (int wq = 0; wq < 8; ++wq) {
        uint4 c4 = cw4[wv * 8 + wq];
        #pragma unroll
        for (int e = 0; e < 4; ++e) {
            uint32_t cw = (e == 0) ? c4.x : (e == 1) ? c4.y : (e == 2) ? c4.z : c4.w;
            // LDS pipe: nibbles 0..4
            float r0 = Tl[0 * 1024 + ((cw >> 0) & 15u) * 64];
            float r1 = Tl[1 * 1024 + ((cw >> 4) & 15u) * 64];
            float r2 = Tl[2 * 1024 + ((cw >> 8) & 15u) * 64];
            float r3 = Tl[3 * 1024 + ((cw >> 12) & 15u) * 64];
            float r4 = Tl[4 * 1024 + ((cw >> 16) & 15u) * 64];
            // VALU pipe: bits 20..31 via sign-bit xor, fixed order
            float vs = 0.0f;
            #pragma unroll
            for (int v = 0; v < NV; ++v)
                vs += __uint_as_float(lau[v] ^ ((cw << (11 - v)) & 0x80000000u));
            float c = ((r0 + r1) + (r2 + r3)) + (r4 + vs);
            uint32_t w = wbase + wq * 4 + e;
            bool g = c > bestf;
            bestw = g ? w : bestw;
            bestf = g ? c : bestf;
        }
    }

    bestf_lds[wv * 64 + l] = bestf;
    bestw_lds[wv * 64 + l] = bestw;
    __syncthreads();

    // Merge 4 waves (ascending w ranges; strict > keeps lower w), then one
    // device-scope atomicMax per batch into its own 64B-padded slot.
    if (tid < B) {
        float f = bestf_lds[tid];
        uint32_t w = bestw_lds[tid];
        #pragma unroll
        for (int v = 1; v < 4; ++v) {
            float f2 = bestf_lds[v * 64 + tid];
            uint32_t w2 = bestw_lds[v * 64 + tid];
            bool g = f2 > f;
            w = g ? w2 : w;
            f = g ? f2 : f;
        }
        uint32_t bits = __float_as_uint(f);
        uint32_t mono = (bits & 0x80000000u) ? ~bits : (bits | 0x80000000u);
        u64 key = ((u64)mono << 16) | (u64)(0xFFFFu - w);
        atomicMax(&slots[tid * SLOT_STRIDE], key);
    }
}

// Kernel 2: single tiny block. Launch boundary guarantees slot visibility.
__global__ __launch_bounds__(256) void mdd_out(
    const u64* __restrict__ slots,     // [B*SLOT_STRIDE]
    float* __restrict__ out)           // [B][K]
{
    __shared__ uint32_t w_lds[B];
    const int tid = threadIdx.x;
    if (tid < B) {
        u64 f = slots[tid * SLOT_STRIDE];
        w_lds[tid] = 0xFFFFu - (uint32_t)(f & 0xFFFFull);
    }
    __syncthreads();
    for (int i = tid; i < B * K; i += 256) {    // coalesced, 4 floats/thread
        int b2 = i >> 4, kk = i & 15;
        out[i] = (float)((w_lds[b2] >> kk) & 1u);
    }
}

extern "C" void kernel_launch(void* const* d_in, const int* in_sizes, int n_in,
                              void* d_out, int out_size, void* d_ws, size_t ws_size,
                              hipStream_t stream) {
    const float* noisy = (const float*)d_in[0];
    const int* G = (const int*)d_in[1];
    const float* sigma2 = (const float*)d_in[2];
    float* out = (float*)d_out;
    u64* slots = (u64*)d_ws;

    (void)in_sizes; (void)n_in; (void)out_size; (void)ws_size;

    hipMemsetAsync(slots, 0, B * SLOT_STRIDE * sizeof(u64), stream);
    mdd_corr<<<BLOCKS, 256, 0, stream>>>(noisy, G, sigma2, slots);
    mdd_out<<<1, 256, 0, stream>>>(slots, out);
}

// Round 7
// 13.388 us; speedup vs baseline: 4.2178x; 1.9987x over previous
//
#include <hip/hip_runtime.h>
#include <stdint.h>

#define B 64
#define N 32
#define K 16
#define NUM_WORDS 65536
#define NBLK 256           // k1 blocks (one per CU)
#define WPB 256            // words per block
#define NTHR 512           // 8 waves per block
#define LLR_PAD 65         // padded stride for transpose staging

typedef unsigned long long u64;

static __device__ __forceinline__ u64 umax64(u64 a, u64 b) { return a > b ? a : b; }

// Kernel 1: lane l = batch l; each wave processes 32 words (wave-uniform cw).
// corr = 4 x 7-bit LDS table lookups (bits 0..27) + 4 sign-xor VALU bits
// (bits 28..31). Per-(block,batch) best key -> plain store to ws[b][block].
// Cross-kernel visibility via the launch boundary (validated rounds 2/3).
__global__ __launch_bounds__(NTHR) void mdd_corr(
    const float* __restrict__ noisy,   // [B][N]
    const int* __restrict__ G,         // [K][N]
    const float* __restrict__ sigma2,  // [1]
    u64* __restrict__ ws)              // [B][NBLK]
{
    __shared__ uint32_t g_rows[K];
    __shared__ __align__(16) uint32_t cw_lds[WPB];
    __shared__ float T_lds[4 * 128 * 64];      // 128 KB: [g][v][lane]
    __shared__ float llr_t[N * LLR_PAD];       // [n][b] padded
    __shared__ float bestf_lds[8 * 64];
    __shared__ uint32_t bestw_lds[8 * 64];

    const int tid = threadIdx.x;
    const int l = tid & 63;
    const int wv = tid >> 6;

    // Pack G rows into 32-bit masks (bit n = G[k][n] & 1)
    if (tid < K) {
        const int4* G4 = reinterpret_cast<const int4*>(G) + tid * 8;
        uint32_t r = 0;
        #pragma unroll
        for (int m = 0; m < 8; ++m) {
            int4 gv = G4[m];
            r |= (uint32_t)(gv.x & 1) << (4 * m + 0);
            r |= (uint32_t)(gv.y & 1) << (4 * m + 1);
            r |= (uint32_t)(gv.z & 1) << (4 * m + 2);
            r |= (uint32_t)(gv.w & 1) << (4 * m + 3);
        }
        g_rows[tid] = r;
    }

    // Coalesced load of noisy, transposed into padded LDS: llr_t[n][b]
    const float scale = -4.0f / sigma2[0];
    for (int i = tid; i < B * N; i += NTHR) {
        int n = i & 31, bb = i >> 5;
        llr_t[n * LLR_PAD + bb] = scale * noisy[i];
    }
    __syncthreads();

    // Codewords for this block's 256 words
    if (tid < WPB) {
        uint32_t w = blockIdx.x * WPB + tid;
        uint32_t cw = 0;
        #pragma unroll
        for (int k = 0; k < K; ++k)
            cw ^= g_rows[k] & (0u - ((w >> k) & 1u));
        cw_lds[tid] = cw;
    }

    // 7-bit tables: T[g][v][l] = sum_{i<7} s((v>>i)&1)*llr[l][7g+i], s(b)=1-2b.
    // Team: wave wv -> group g = wv&3, half h = wv>>2 (v = h*64 + j).
    // Balanced exactly-negated trees, compile-time indices only (no scratch).
    {
        const int g = wv & 3, h = wv >> 2;
        float l0 = llr_t[(7 * g + 0) * LLR_PAD + l];
        float l1 = llr_t[(7 * g + 1) * LLR_PAD + l];
        float l2 = llr_t[(7 * g + 2) * LLR_PAD + l];
        float l3 = llr_t[(7 * g + 3) * LLR_PAD + l];
        float l4 = llr_t[(7 * g + 4) * LLR_PAD + l];
        float l5 = llr_t[(7 * g + 5) * LLR_PAD + l];
        float l6 = llr_t[(7 * g + 6) * LLR_PAD + l];
        float l6s = h ? -l6 : l6;                  // bit 6 of v == h
        float P[4] = { l0 + l1, -l0 + l1, l0 - l1, -l0 - l1 };
        float A[8];
        #pragma unroll
        for (int a = 0; a < 8; ++a)
            A[a] = (a & 4) ? (P[a & 3] - l2) : (P[a & 3] + l2);
        float Q[4] = { l3 + l4, -l3 + l4, l3 - l4, -l3 - l4 };
        float R[8];
        #pragma unroll
        for (int r = 0; r < 8; ++r)
            R[r] = (r & 4) ? (Q[r & 3] - l5) : (Q[r & 3] + l5);
        float Cp[8];
        #pragma unroll
        for (int c = 0; c < 8; ++c)
            Cp[c] = R[c] + l6s;
        float* Tg = &T_lds[g * 8192 + h * 64 * 64 + l];
        #pragma unroll
        for (int j = 0; j < 64; ++j)
            Tg[j * 64] = A[j & 7] + Cp[j >> 3];
    }

    // This lane's llr bit-patterns for bits 28..31 (VALU sign-xor path)
    uint32_t lau0 = __float_as_uint(llr_t[28 * LLR_PAD + l]);
    uint32_t lau1 = __float_as_uint(llr_t[29 * LLR_PAD + l]);
    uint32_t lau2 = __float_as_uint(llr_t[30 * LLR_PAD + l]);
    uint32_t lau3 = __float_as_uint(llr_t[31 * LLR_PAD + l]);
    __syncthreads();

    // Main loop: 32 words/thread, strict > with ascending w => first-wins
    const uint4* cw4 = reinterpret_cast<const uint4*>(cw_lds);
    const float* Tl = &T_lds[l];
    float bestf = -INFINITY;
    uint32_t bestw = 0;
    const uint32_t wbase = blockIdx.x * WPB + wv * 32;

    #pragma unroll
    for (int wq = 0; wq < 8; ++wq) {
        uint4 c4 = cw4[wv * 8 + wq];
        #pragma unroll
        for (int e = 0; e < 4; ++e) {
            uint32_t cw = (e == 0) ? c4.x : (e == 1) ? c4.y : (e == 2) ? c4.z : c4.w;
            // LDS pipe: 4 x 7-bit groups
            float r0 = Tl[0 * 8192 + ((cw >> 0) & 127u) * 64];
            float r1 = Tl[1 * 8192 + ((cw >> 7) & 127u) * 64];
            float r2 = Tl[2 * 8192 + ((cw >> 14) & 127u) * 64];
            float r3 = Tl[3 * 8192 + ((cw >> 21) & 127u) * 64];
            // VALU pipe: bits 28..31 via sign-bit xor (fixed order)
            float v0 = __uint_as_float(lau0 ^ ((cw << 3) & 0x80000000u));
            float v1 = __uint_as_float(lau1 ^ ((cw << 2) & 0x80000000u));
            float v2 = __uint_as_float(lau2 ^ ((cw << 1) & 0x80000000u));
            float v3 = __uint_as_float(lau3 ^ ((cw << 0) & 0x80000000u));
            float c = ((r0 + r1) + (r2 + r3)) + ((v0 + v1) + (v2 + v3));
            uint32_t w = wbase + wq * 4 + e;
            bool g = c > bestf;
            bestw = g ? w : bestw;
            bestf = g ? c : bestf;
        }
    }

    bestf_lds[wv * 64 + l] = bestf;
    bestw_lds[wv * 64 + l] = bestw;
    __syncthreads();

    // Merge 8 waves (ascending w ranges; strict > keeps lower w), store key.
    // Scattered 8B stores (64 lines), fire-and-forget before block exit.
    if (tid < B) {
        float f = bestf_lds[tid];
        uint32_t w = bestw_lds[tid];
        #pragma unroll
        for (int v = 1; v < 8; ++v) {
            float f2 = bestf_lds[v * 64 + tid];
            uint32_t w2 = bestw_lds[v * 64 + tid];
            bool g = f2 > f;
            w = g ? w2 : w;
            f = g ? f2 : f;
        }
        uint32_t bits = __float_as_uint(f);
        uint32_t mono = (bits & 0x80000000u) ? ~bits : (bits | 0x80000000u);
        u64 key = ((u64)mono << 16) | (u64)(0xFFFFu - w);
        ws[(size_t)tid * NBLK + blockIdx.x] = key;
    }
}

// Kernel 2: one wave per batch; fully coalesced 2KB row read; decode bits.
__global__ __launch_bounds__(64) void mdd_out(
    const u64* __restrict__ ws,        // [B][NBLK]
    float* __restrict__ out)           // [B][K]
{
    const int b = blockIdx.x;
    const int t = threadIdx.x;
    const u64* p = ws + (size_t)b * NBLK;

    u64 m = umax64(umax64(p[t], p[t + 64]), umax64(p[t + 128], p[t + 192]));
    #pragma unroll
    for (int off = 32; off > 0; off >>= 1) {
        u64 o = __shfl_xor(m, off, 64);
        m = umax64(m, o);
    }
    uint32_t w = 0xFFFFu - (uint32_t)(m & 0xFFFFull);
    if (t < K) out[b * K + t] = (float)((w >> t) & 1u);
}

extern "C" void kernel_launch(void* const* d_in, const int* in_sizes, int n_in,
                              void* d_out, int out_size, void* d_ws, size_t ws_size,
                              hipStream_t stream) {
    const float* noisy = (const float*)d_in[0];
    const int* G = (const int*)d_in[1];
    const float* sigma2 = (const float*)d_in[2];
    float* out = (float*)d_out;
    u64* ws = (u64*)d_ws;

    (void)in_sizes; (void)n_in; (void)out_size; (void)ws_size;

    mdd_corr<<<NBLK, NTHR, 0, stream>>>(noisy, G, sigma2, ws);
    mdd_out<<<B, 64, 0, stream>>>(ws, out);
}